// Round 2
// baseline (9.613 us; speedup 1.0000x reference)
//
#include <hip/hip_runtime.h>
#include <math.h>

// Izhikevich 'RS' params + constants from the reference
#define A_P 0.02f
#define B_P 0.2f
#define C_P -65.0f
#define D_P 8.0f
#define I_TONIC -1.5f
#define V_SPIKE 30.0f
#define RATE_DECAY 0.95f
#define OSC_FREQ 0.04f
#define TWO_PI 6.28318530717958647692f
// (1 - PC_TAU)^8 = 0.875^8 and its complement
#define PC_K 0.34360891580581665f
#define PC_1MK 0.65639108419418335f

__global__ void __launch_bounds__(64)
SpikingInferiorOlive_kernel(const float* __restrict__ sensory_surprise,
                            const float* __restrict__ motor_mismatch,
                            const float* __restrict__ cerebellar_pe,
                            const float* __restrict__ prev_sensory,
                            const float* __restrict__ prev_motor,
                            const float* __restrict__ osc_phase,
                            const float* __restrict__ v0,
                            const float* __restrict__ u0,
                            const float* __restrict__ rate0,
                            const float* __restrict__ noise,   // [10][8]
                            const float* __restrict__ pc_m0,
                            float* __restrict__ out)           // 16 floats
{
    const int lane = threadIdx.x;
    const int n    = lane & 7;      // lanes replicate mod 8 -> zero divergence

    // ---- uniform scalar front-end (all lanes, broadcast loads) ----
    const float s   = sensory_surprise[0];
    const float m   = motor_mismatch[0];
    const float cpe = cerebellar_pe[0];

    const float delta_sensory = fabsf(s - prev_sensory[0]);
    const float sensory_error = fminf(1.0f, delta_sensory + s * 0.3f);
    const float delta_motor   = fabsf(m - prev_motor[0]);
    const float motor_error   = fminf(1.0f, delta_motor + m * 0.3f);

    const float phase = osc_phase[0] + OSC_FREQ;
    const float osc   = 0.15f * sinf(TWO_PI * phase);

    const float raw_cf = sensory_error * 0.4f + motor_error * 0.4f + cpe * 0.2f;
    const bool  is_cs  = raw_cf > 0.2f;
    const float climbing_fiber = is_cs ? fminf(1.0f, raw_cf * 1.5f)
                                       : fmaxf(0.0f, raw_cf + osc);

    // ---- per-lane input current (cndmask chain, no scratch array) ----
    float I =            sensory_error * 15.0f;        // n==0
    I = (n == 1) ? delta_sensory * 12.0f  : I;
    I = (n == 2) ? sensory_error * 8.0f   : I;
    I = (n == 3) ? osc * 5.0f + 2.0f      : I;
    I = (n == 4) ? motor_error * 15.0f    : I;
    I = (n == 5) ? delta_motor * 12.0f    : I;
    I = (n == 6) ? motor_error * 8.0f     : I;
    I = (n == 7) ? climbing_fiber * 10.0f : I;

    // ---- Izhikevich scan: one neuron per lane, 10 steps ----
    float v = v0[n], u = u0[n], r = rate0[n];
#pragma unroll
    for (int t = 0; t < 10; ++t) {
        const float Ii = I + noise[t * 8 + n] * 0.3f + I_TONIC;
        const float dv = 0.04f * v * v + 5.0f * v + 140.0f - u + Ii;
        const float du = A_P * (B_P * v - u);
        v = v + dv;
        u = u + du;
        const bool sp = (v >= V_SPIKE);
        if (sp) { v = C_P; u += D_P; }
        r = RATE_DECAY * r + (1.0f - RATE_DECAY) * (sp ? 1.0f : 0.0f);
    }

    // ---- TwoCompColumn, closed form of 8 leaky-integrator substeps ----
    const float drive = (n < 4) ? sensory_error : motor_error;
    const float mem   = PC_K * pc_m0[n] + PC_1MK * drive;

    // 4-group mean -> pe for own channel; xor-4 fetches the other channel
    float psum = mem;
    psum += __shfl_xor(psum, 1);
    psum += __shfl_xor(psum, 2);
    const float pe_self  = psum * 0.25f;
    const float pe_other = __shfl_xor(pe_self, 4);
    const float pe0 = (n < 4) ? pe_self : pe_other;
    const float pe1 = (n < 4) ? pe_other : pe_self;

    const float prec0 = 1.0f / (1.0f + pe0 * pe0);
    const float prec1 = 1.0f / (1.0f + pe1 * pe1);
    const float free_energy      = 0.5f * (prec0 * pe0 * pe0 + prec1 * pe1 * pe1);
    const float prediction_error = 0.5f * (fabsf(pe0) + fabsf(pe1));
    const float precision_mean   = 0.5f * (prec0 + prec1);

    // ---- rate mean across the 8 neurons ----
    float rsum = r;
    rsum += __shfl_xor(rsum, 1);
    rsum += __shfl_xor(rsum, 2);
    rsum += __shfl_xor(rsum, 4);
    const float rate_mean = rsum * 0.125f;

    // ---- stores: two float4 from lane 0, one coalesced dword per lane 0-7 ----
    if (lane == 0) {
        float4 o0 = make_float4(sensory_error, motor_error, climbing_fiber,
                                is_cs ? 1.0f : 0.0f);
        float4 o1 = make_float4(prediction_error, precision_mean,
                                free_energy, rate_mean);
        *reinterpret_cast<float4*>(out)     = o0;
        *reinterpret_cast<float4*>(out + 4) = o1;
    }
    if (lane < 8) out[8 + lane] = r;
}

extern "C" void kernel_launch(void* const* d_in, const int* in_sizes, int n_in,
                              void* d_out, int out_size, void* d_ws, size_t ws_size,
                              hipStream_t stream) {
    (void)in_sizes; (void)n_in; (void)d_ws; (void)ws_size; (void)out_size;
    SpikingInferiorOlive_kernel<<<1, 64, 0, stream>>>(
        (const float*)d_in[0],  // sensory_surprise
        (const float*)d_in[1],  // motor_mismatch
        (const float*)d_in[2],  // cerebellar_pe
        (const float*)d_in[3],  // prev_sensory
        (const float*)d_in[4],  // prev_motor
        (const float*)d_in[5],  // osc_phase
        (const float*)d_in[6],  // v0
        (const float*)d_in[7],  // u0
        (const float*)d_in[8],  // rate0
        (const float*)d_in[9],  // noise [10][8]
        (const float*)d_in[10], // pc_m0
        (float*)d_out);
}